// Round 1
// baseline (2854.336 us; speedup 1.0000x reference)
//
#include <hip/hip_runtime.h>
#include <math.h>

#define NB   8
#define LLEN 2048
#define HDIM 1024
#define LNEPS 1e-5f

#define BM 64
#define BN 64
#define BK 16

// C = alpha * (A @ B + bias); A: MxK row-major, B: KxN row-major, C: MxN
__global__ __launch_bounds__(256) void gemm_bias_kernel(
    const float* __restrict__ A, const float* __restrict__ B,
    const float* __restrict__ bias, float* __restrict__ C,
    int M, int Nn, int Kk, float alpha)
{
    __shared__ float As[BK][BM];
    __shared__ float Bs[BK][BN];
    const int t  = threadIdx.x;
    const int tx = t & 15, ty = t >> 4;
    const int rowBase = blockIdx.y * BM;
    const int colBase = blockIdx.x * BN;
    const int ar = t >> 2;          // A-tile row this thread loads
    const int ak = (t & 3) * 4;     // A-tile k offset (float4)
    const int bk_ = t >> 4;         // B-tile k this thread loads
    const int bc  = (t & 15) * 4;   // B-tile col offset (float4)

    float acc[4][4] = {{0.f,0.f,0.f,0.f},{0.f,0.f,0.f,0.f},
                       {0.f,0.f,0.f,0.f},{0.f,0.f,0.f,0.f}};

    for (int k0 = 0; k0 < Kk; k0 += BK) {
        float4 av = *reinterpret_cast<const float4*>(
            &A[(size_t)(rowBase + ar) * Kk + (k0 + ak)]);
        float4 bv = *reinterpret_cast<const float4*>(
            &B[(size_t)(k0 + bk_) * Nn + (colBase + bc)]);
        As[ak+0][ar] = av.x; As[ak+1][ar] = av.y;
        As[ak+2][ar] = av.z; As[ak+3][ar] = av.w;
        *reinterpret_cast<float4*>(&Bs[bk_][bc]) = bv;
        __syncthreads();
        #pragma unroll
        for (int k = 0; k < BK; ++k) {
            float4 a = *reinterpret_cast<const float4*>(&As[k][ty*4]);
            float4 b = *reinterpret_cast<const float4*>(&Bs[k][tx*4]);
            float ai[4] = {a.x,a.y,a.z,a.w};
            float bj[4] = {b.x,b.y,b.z,b.w};
            #pragma unroll
            for (int i = 0; i < 4; ++i)
                #pragma unroll
                for (int j = 0; j < 4; ++j)
                    acc[i][j] = fmaf(ai[i], bj[j], acc[i][j]);
        }
        __syncthreads();
    }

    #pragma unroll
    for (int i = 0; i < 4; ++i) {
        const int row = rowBase + ty*4 + i;
        float4 bb = *reinterpret_cast<const float4*>(&bias[colBase + tx*4]);
        float4 o;
        o.x = alpha * (acc[i][0] + bb.x);
        o.y = alpha * (acc[i][1] + bb.y);
        o.z = alpha * (acc[i][2] + bb.z);
        o.w = alpha * (acc[i][3] + bb.w);
        *reinterpret_cast<float4*>(&C[(size_t)row * Nn + colBase + tx*4]) = o;
    }
}

// Per batch n: A[a,b] = Q[n,a,:]·K[n,b,:]. Accumulate colsum[n,b] += sum_a exp(A[a,b]),
// and record diagval[n,l] = A[l,l] on diagonal tiles. (No max-subtraction: |A| < ~1.)
__global__ __launch_bounds__(256) void qk_diag_kernel(
    const float* __restrict__ Q, const float* __restrict__ K,
    float* __restrict__ colsum, float* __restrict__ diagval)
{
    __shared__ float As[BK][BM];
    __shared__ float Bs[BK][BN];
    const int t  = threadIdx.x;
    const int tx = t & 15, ty = t >> 4;
    const int n = blockIdx.z;
    const int aBase = blockIdx.y * BM;
    const int bBase = blockIdx.x * BN;
    const float* Qn = Q + (size_t)n * LLEN * HDIM;
    const float* Kn = K + (size_t)n * LLEN * HDIM;
    const int ar = t >> 2;
    const int ak = (t & 3) * 4;

    float acc[4][4] = {{0.f,0.f,0.f,0.f},{0.f,0.f,0.f,0.f},
                       {0.f,0.f,0.f,0.f},{0.f,0.f,0.f,0.f}};

    for (int k0 = 0; k0 < HDIM; k0 += BK) {
        float4 av = *reinterpret_cast<const float4*>(
            &Qn[(size_t)(aBase + ar) * HDIM + (k0 + ak)]);
        float4 bv = *reinterpret_cast<const float4*>(
            &Kn[(size_t)(bBase + ar) * HDIM + (k0 + ak)]);
        As[ak+0][ar] = av.x; As[ak+1][ar] = av.y;
        As[ak+2][ar] = av.z; As[ak+3][ar] = av.w;
        Bs[ak+0][ar] = bv.x; Bs[ak+1][ar] = bv.y;
        Bs[ak+2][ar] = bv.z; Bs[ak+3][ar] = bv.w;
        __syncthreads();
        #pragma unroll
        for (int k = 0; k < BK; ++k) {
            float4 a = *reinterpret_cast<const float4*>(&As[k][ty*4]);
            float4 b = *reinterpret_cast<const float4*>(&Bs[k][tx*4]);
            float ai[4] = {a.x,a.y,a.z,a.w};
            float bj[4] = {b.x,b.y,b.z,b.w};
            #pragma unroll
            for (int i = 0; i < 4; ++i)
                #pragma unroll
                for (int j = 0; j < 4; ++j)
                    acc[i][j] = fmaf(ai[i], bj[j], acc[i][j]);
        }
        __syncthreads();
    }

    // exp + per-thread partial column sums (4 columns per thread)
    float csum[4] = {0.f, 0.f, 0.f, 0.f};
    #pragma unroll
    for (int i = 0; i < 4; ++i)
        #pragma unroll
        for (int j = 0; j < 4; ++j)
            csum[j] += expf(acc[i][j]);

    // reduce across ty (16 partials per column) via LDS (reuse As: [16][64])
    #pragma unroll
    for (int j = 0; j < 4; ++j) As[ty][tx*4 + j] = csum[j];
    __syncthreads();
    if (t < 64) {
        float s = 0.f;
        #pragma unroll
        for (int y = 0; y < 16; ++y) s += As[y][t];
        atomicAdd(&colsum[(size_t)n * LLEN + bBase + t], s);
    }

    // diagonal entries (only on diagonal tiles; unique writer per element)
    if (aBase == bBase && tx == ty) {
        #pragma unroll
        for (int i = 0; i < 4; ++i)
            diagval[(size_t)n * LLEN + aBase + ty*4 + i] = acc[i][i];
    }
}

// h1 = LayerNorm(diag*V + X) * g1 + b1 ; one block (256 thr) per row, float4 lanes
__global__ __launch_bounds__(256) void ln1_kernel(
    const float* __restrict__ V, const float* __restrict__ X,
    const float* __restrict__ colsum, const float* __restrict__ diagval,
    const float* __restrict__ g1, const float* __restrict__ b1,
    float* __restrict__ h1)
{
    const int row = blockIdx.x;
    const size_t base = (size_t)row * HDIM;
    const float dv = expf(diagval[row]) / colsum[row];
    const int h0 = threadIdx.x * 4;

    float4 vv = *reinterpret_cast<const float4*>(&V[base + h0]);
    float4 xx = *reinterpret_cast<const float4*>(&X[base + h0]);
    float y[4];
    y[0] = dv*vv.x + xx.x; y[1] = dv*vv.y + xx.y;
    y[2] = dv*vv.z + xx.z; y[3] = dv*vv.w + xx.w;

    float s = y[0]+y[1]+y[2]+y[3];
    float s2 = y[0]*y[0]+y[1]*y[1]+y[2]*y[2]+y[3]*y[3];
    #pragma unroll
    for (int off = 32; off > 0; off >>= 1) {
        s  += __shfl_down(s,  off);
        s2 += __shfl_down(s2, off);
    }
    __shared__ float ws1[4], ws2[4];
    const int wid = threadIdx.x >> 6;
    if ((threadIdx.x & 63) == 0) { ws1[wid] = s; ws2[wid] = s2; }
    __syncthreads();
    const float S  = ws1[0]+ws1[1]+ws1[2]+ws1[3];
    const float S2 = ws2[0]+ws2[1]+ws2[2]+ws2[3];
    const float m   = S  * (1.0f / HDIM);
    const float var = S2 * (1.0f / HDIM) - m*m;
    const float inv = rsqrtf(var + LNEPS);

    float4 gg = *reinterpret_cast<const float4*>(&g1[h0]);
    float4 bb = *reinterpret_cast<const float4*>(&b1[h0]);
    float4 o;
    o.x = (y[0]-m)*inv*gg.x + bb.x;
    o.y = (y[1]-m)*inv*gg.y + bb.y;
    o.z = (y[2]-m)*inv*gg.z + bb.z;
    o.w = (y[3]-m)*inv*gg.w + bb.w;
    *reinterpret_cast<float4*>(&h1[base + h0]) = o;
}

// out = LayerNorm(G + h1) * g2 + b2
__global__ __launch_bounds__(256) void ln2_kernel(
    const float* __restrict__ G, const float* __restrict__ h1res,
    const float* __restrict__ g2, const float* __restrict__ b2,
    float* __restrict__ out)
{
    const int row = blockIdx.x;
    const size_t base = (size_t)row * HDIM;
    const int h0 = threadIdx.x * 4;

    float4 gv = *reinterpret_cast<const float4*>(&G[base + h0]);
    float4 hv = *reinterpret_cast<const float4*>(&h1res[base + h0]);
    float y[4];
    y[0] = gv.x + hv.x; y[1] = gv.y + hv.y;
    y[2] = gv.z + hv.z; y[3] = gv.w + hv.w;

    float s = y[0]+y[1]+y[2]+y[3];
    float s2 = y[0]*y[0]+y[1]*y[1]+y[2]*y[2]+y[3]*y[3];
    #pragma unroll
    for (int off = 32; off > 0; off >>= 1) {
        s  += __shfl_down(s,  off);
        s2 += __shfl_down(s2, off);
    }
    __shared__ float ws1[4], ws2[4];
    const int wid = threadIdx.x >> 6;
    if ((threadIdx.x & 63) == 0) { ws1[wid] = s; ws2[wid] = s2; }
    __syncthreads();
    const float S  = ws1[0]+ws1[1]+ws1[2]+ws1[3];
    const float S2 = ws2[0]+ws2[1]+ws2[2]+ws2[3];
    const float m   = S  * (1.0f / HDIM);
    const float var = S2 * (1.0f / HDIM) - m*m;
    const float inv = rsqrtf(var + LNEPS);

    float4 gg = *reinterpret_cast<const float4*>(&g2[h0]);
    float4 bb = *reinterpret_cast<const float4*>(&b2[h0]);
    float4 o;
    o.x = (y[0]-m)*inv*gg.x + bb.x;
    o.y = (y[1]-m)*inv*gg.y + bb.y;
    o.z = (y[2]-m)*inv*gg.z + bb.z;
    o.w = (y[3]-m)*inv*gg.w + bb.w;
    *reinterpret_cast<float4*>(&out[base + h0]) = o;
}

extern "C" void kernel_launch(void* const* d_in, const int* in_sizes, int n_in,
                              void* d_out, int out_size, void* d_ws, size_t ws_size,
                              hipStream_t stream) {
    (void)in_sizes; (void)n_in; (void)out_size; (void)ws_size;
    const float* X  = (const float*)d_in[0];
    const float* Wq = (const float*)d_in[1];
    const float* bq = (const float*)d_in[2];
    const float* Wk = (const float*)d_in[3];
    const float* bk = (const float*)d_in[4];
    const float* Wv = (const float*)d_in[5];
    const float* bv = (const float*)d_in[6];
    const float* Wf = (const float*)d_in[7];
    const float* bf = (const float*)d_in[8];
    const float* g1 = (const float*)d_in[9];
    const float* b1 = (const float*)d_in[10];
    const float* g2 = (const float*)d_in[11];
    const float* b2 = (const float*)d_in[12];
    float* out = (float*)d_out;
    float* ws  = (float*)d_ws;

    const size_t MAT = (size_t)NB * LLEN * HDIM;   // 16,777,216 floats
    float* Qbuf   = ws;                 // 64 MB
    float* Kbuf   = ws + MAT;           // 64 MB
    float* colsum = ws + 2 * MAT;       // 64 KB
    float* diagv  = colsum + NB * LLEN; // 64 KB
    float* Vbuf   = out;                // stage V in d_out (overwritten at the end)
    float* h1buf  = Qbuf;               // reuse after qk_diag
    float* Gbuf   = Kbuf;               // reuse after qk_diag

    const int M = NB * LLEN;            // 16384 rows
    const float scale = 1.0f / 32.0f;   // 1/sqrt(H)

    hipMemsetAsync(colsum, 0, (size_t)NB * LLEN * sizeof(float), stream);

    dim3 blk(256);
    dim3 ggrid(HDIM / BN, M / BM);
    gemm_bias_kernel<<<ggrid, blk, 0, stream>>>(X, Wq, bq, Qbuf, M, HDIM, HDIM, scale);
    gemm_bias_kernel<<<ggrid, blk, 0, stream>>>(X, Wk, bk, Kbuf, M, HDIM, HDIM, scale);
    gemm_bias_kernel<<<ggrid, blk, 0, stream>>>(X, Wv, bv, Vbuf, M, HDIM, HDIM, 1.0f);

    dim3 qgrid(LLEN / BN, LLEN / BM, NB);
    qk_diag_kernel<<<qgrid, blk, 0, stream>>>(Qbuf, Kbuf, colsum, diagv);

    ln1_kernel<<<M, blk, 0, stream>>>(Vbuf, X, colsum, diagv, g1, b1, h1buf);

    gemm_bias_kernel<<<ggrid, blk, 0, stream>>>(h1buf, Wf, bf, Gbuf, M, HDIM, HDIM, 1.0f);

    ln2_kernel<<<M, blk, 0, stream>>>(Gbuf, h1buf, g2, b2, out);
}

// Round 2
// 401.426 us; speedup vs baseline: 7.1105x; 7.1105x over previous
//
#include <hip/hip_runtime.h>
#include <math.h>

#define NB   8
#define LLEN 2048
#define HDIM 1024
#define LNEPS 1e-5f

#define TM 128
#define TN 128
#define TK 32

typedef __attribute__((ext_vector_type(8))) short short8;
typedef __attribute__((ext_vector_type(4))) unsigned short ushort4v;
typedef __attribute__((ext_vector_type(4))) float f32x4;

typedef __attribute__((address_space(3))) void lds_void;
typedef const __attribute__((address_space(1))) void glob_void;

__device__ __forceinline__ unsigned short f2bf(float f) {
    union { float f; unsigned u; } v; v.f = f;
    unsigned r = v.u + 0x7FFFu + ((v.u >> 16) & 1u);
    return (unsigned short)(r >> 16);
}
__device__ __forceinline__ float bf2f(unsigned short h) {
    union { unsigned u; float f; } v; v.u = ((unsigned)h) << 16;
    return v.f;
}

// ---- fp32 -> bf16 cast, 8 elems/thread ----
__global__ __launch_bounds__(256) void cast_f32_bf16(
    const float* __restrict__ in, unsigned short* __restrict__ outp, int n8)
{
    int i = blockIdx.x * 256 + threadIdx.x;
    if (i >= n8) return;
    const float4* p = reinterpret_cast<const float4*>(in) + (size_t)i * 2;
    float4 a = p[0], b = p[1];
    short8 o;
    o[0] = (short)f2bf(a.x); o[1] = (short)f2bf(a.y);
    o[2] = (short)f2bf(a.z); o[3] = (short)f2bf(a.w);
    o[4] = (short)f2bf(b.x); o[5] = (short)f2bf(b.y);
    o[6] = (short)f2bf(b.z); o[7] = (short)f2bf(b.w);
    *(reinterpret_cast<short8*>(outp) + i) = o;
}

// ---- W (K x N fp32) -> Wt (N x K bf16) ----
__global__ __launch_bounds__(256) void transpose_cast(
    const float* __restrict__ W, unsigned short* __restrict__ Wt)
{
    __shared__ float tile[32][33];
    const int tx = threadIdx.x & 31, ty = threadIdx.x >> 5; // ty 0..7
    const int c0 = blockIdx.x * 32, r0 = blockIdx.y * 32;
    #pragma unroll
    for (int r = 0; r < 4; ++r)
        tile[ty + r*8][tx] = W[(size_t)(r0 + ty + r*8) * HDIM + c0 + tx];
    __syncthreads();
    #pragma unroll
    for (int r = 0; r < 4; ++r)
        Wt[(size_t)(c0 + ty + r*8) * HDIM + r0 + tx] = f2bf(tile[tx][ty + r*8]);
}

// ---- C = bf16( alpha * (A @ Bt^T + bias) ); A: MxK bf16, Bt: NxK bf16 ----
__global__ __launch_bounds__(256) void gemm_nt_bf16(
    const unsigned short* __restrict__ A,
    const unsigned short* __restrict__ Bt,
    const float* __restrict__ bias,
    unsigned short* __restrict__ C,
    int M, int Nn, int Kk, float alpha)
{
    __shared__ __align__(16) unsigned short lA[TM * TK];
    __shared__ __align__(16) unsigned short lB[TN * TK];
    const int t = threadIdx.x;
    const int w = t >> 6, l = t & 63;
    const int wm = w >> 1, wn = w & 1;
    const int rowBase = blockIdx.y * TM;
    const int colBase = blockIdx.x * TN;
    const int lr = l & 15, lk = (l >> 4) * 8;
    const int srow = (w << 4) + (l >> 2);   // staging row within 64-row half
    const int skk  = (l & 3) * 8;           // staging k offset

    f32x4 acc[4][4] = {};

    for (int k0 = 0; k0 < Kk; k0 += TK) {
        #pragma unroll
        for (int i = 0; i < 2; ++i) {
            __builtin_amdgcn_global_load_lds(
                (glob_void*)(A + (size_t)(rowBase + i*64 + srow) * Kk + k0 + skk),
                (lds_void*)(lA + i*2048 + w*512), 16, 0, 0);
            __builtin_amdgcn_global_load_lds(
                (glob_void*)(Bt + (size_t)(colBase + i*64 + srow) * Kk + k0 + skk),
                (lds_void*)(lB + i*2048 + w*512), 16, 0, 0);
        }
        __syncthreads();
        short8 af[4], bfr[4];
        #pragma unroll
        for (int mi = 0; mi < 4; ++mi)
            af[mi] = *reinterpret_cast<const short8*>(&lA[(wm*64 + mi*16 + lr) * TK + lk]);
        #pragma unroll
        for (int ni = 0; ni < 4; ++ni)
            bfr[ni] = *reinterpret_cast<const short8*>(&lB[(wn*64 + ni*16 + lr) * TK + lk]);
        #pragma unroll
        for (int mi = 0; mi < 4; ++mi)
            #pragma unroll
            for (int ni = 0; ni < 4; ++ni)
                acc[mi][ni] = __builtin_amdgcn_mfma_f32_16x16x32_bf16(
                    af[mi], bfr[ni], acc[mi][ni], 0, 0, 0);
        __syncthreads();
    }

    #pragma unroll
    for (int ni = 0; ni < 4; ++ni) {
        const int col = colBase + wn*64 + ni*16 + lr;
        const float bv = bias[col];
        #pragma unroll
        for (int mi = 0; mi < 4; ++mi) {
            const int row0 = rowBase + wm*64 + mi*16 + (l >> 4) * 4;
            #pragma unroll
            for (int j = 0; j < 4; ++j)
                C[(size_t)(row0 + j) * Nn + col] = f2bf(alpha * (acc[mi][ni][j] + bv));
        }
    }
}

// ---- per batch: A[a,b] = Q[a,:]·K[b,:]; colsum[b] += sum_a exp(A[a,b]); diag[l]=A[l,l] ----
__global__ __launch_bounds__(256) void qk_colsum_diag(
    const unsigned short* __restrict__ Q,
    const unsigned short* __restrict__ K,
    float* __restrict__ colsum, float* __restrict__ diagv)
{
    __shared__ __align__(16) unsigned short lA[TM * TK];
    __shared__ __align__(16) unsigned short lB[TN * TK];
    const int t = threadIdx.x;
    const int w = t >> 6, l = t & 63;
    const int wm = w >> 1, wn = w & 1;
    const int n = blockIdx.z;
    const unsigned short* Qn = Q + (size_t)n * LLEN * HDIM;
    const unsigned short* Kn = K + (size_t)n * LLEN * HDIM;
    const int rowBase = blockIdx.y * TM;
    const int colBase = blockIdx.x * TN;
    const int lr = l & 15, lk = (l >> 4) * 8;
    const int srow = (w << 4) + (l >> 2);
    const int skk  = (l & 3) * 8;

    f32x4 acc[4][4] = {};

    for (int k0 = 0; k0 < HDIM; k0 += TK) {
        #pragma unroll
        for (int i = 0; i < 2; ++i) {
            __builtin_amdgcn_global_load_lds(
                (glob_void*)(Qn + (size_t)(rowBase + i*64 + srow) * HDIM + k0 + skk),
                (lds_void*)(lA + i*2048 + w*512), 16, 0, 0);
            __builtin_amdgcn_global_load_lds(
                (glob_void*)(Kn + (size_t)(colBase + i*64 + srow) * HDIM + k0 + skk),
                (lds_void*)(lB + i*2048 + w*512), 16, 0, 0);
        }
        __syncthreads();
        short8 af[4], bfr[4];
        #pragma unroll
        for (int mi = 0; mi < 4; ++mi)
            af[mi] = *reinterpret_cast<const short8*>(&lA[(wm*64 + mi*16 + lr) * TK + lk]);
        #pragma unroll
        for (int ni = 0; ni < 4; ++ni)
            bfr[ni] = *reinterpret_cast<const short8*>(&lB[(wn*64 + ni*16 + lr) * TK + lk]);
        #pragma unroll
        for (int mi = 0; mi < 4; ++mi)
            #pragma unroll
            for (int ni = 0; ni < 4; ++ni)
                acc[mi][ni] = __builtin_amdgcn_mfma_f32_16x16x32_bf16(
                    af[mi], bfr[ni], acc[mi][ni], 0, 0, 0);
        __syncthreads();
    }

    // column sums of exp over this block's 128 rows (wave covers 64 rows)
    #pragma unroll
    for (int ni = 0; ni < 4; ++ni) {
        float s = 0.f;
        #pragma unroll
        for (int mi = 0; mi < 4; ++mi)
            #pragma unroll
            for (int j = 0; j < 4; ++j)
                s += __expf(acc[mi][ni][j]);
        s += __shfl_xor(s, 16);
        s += __shfl_xor(s, 32);
        if (l < 16)
            atomicAdd(&colsum[(size_t)n * LLEN + colBase + wn*64 + ni*16 + l], s);
    }

    // diagonal entries (pre-exp)
    if (rowBase == colBase && wm == wn) {
        #pragma unroll
        for (int mi = 0; mi < 4; ++mi)
            #pragma unroll
            for (int j = 0; j < 4; ++j)
                if (((l >> 4) * 4 + j) == lr)
                    diagv[(size_t)n * LLEN + rowBase + wm*64 + mi*16 + lr] = acc[mi][mi][j];
    }
}

// ---- h1 = bf16( LN(diag*V + X) * g1 + b1 ) ----
__global__ __launch_bounds__(256) void ln1_kernel(
    const unsigned short* __restrict__ Vb, const float* __restrict__ X,
    const float* __restrict__ colsum, const float* __restrict__ diagval,
    const float* __restrict__ g1, const float* __restrict__ b1,
    unsigned short* __restrict__ h1)
{
    const int row = blockIdx.x;
    const size_t base = (size_t)row * HDIM;
    const float dv = __expf(diagval[row]) / colsum[row];
    const int h0 = threadIdx.x * 4;

    ushort4v vv = *reinterpret_cast<const ushort4v*>(&Vb[base + h0]);
    float4 xx = *reinterpret_cast<const float4*>(&X[base + h0]);
    float y[4];
    y[0] = dv * bf2f(vv[0]) + xx.x; y[1] = dv * bf2f(vv[1]) + xx.y;
    y[2] = dv * bf2f(vv[2]) + xx.z; y[3] = dv * bf2f(vv[3]) + xx.w;

    float s = y[0]+y[1]+y[2]+y[3];
    float s2 = y[0]*y[0]+y[1]*y[1]+y[2]*y[2]+y[3]*y[3];
    #pragma unroll
    for (int off = 32; off > 0; off >>= 1) {
        s  += __shfl_down(s,  off);
        s2 += __shfl_down(s2, off);
    }
    __shared__ float ws1[4], ws2[4];
    const int wid = threadIdx.x >> 6;
    if ((threadIdx.x & 63) == 0) { ws1[wid] = s; ws2[wid] = s2; }
    __syncthreads();
    const float S  = ws1[0]+ws1[1]+ws1[2]+ws1[3];
    const float S2 = ws2[0]+ws2[1]+ws2[2]+ws2[3];
    const float m   = S  * (1.0f / HDIM);
    const float var = S2 * (1.0f / HDIM) - m*m;
    const float inv = rsqrtf(var + LNEPS);

    float4 gg = *reinterpret_cast<const float4*>(&g1[h0]);
    float4 bb = *reinterpret_cast<const float4*>(&b1[h0]);
    ushort4v o;
    o[0] = f2bf((y[0]-m)*inv*gg.x + bb.x);
    o[1] = f2bf((y[1]-m)*inv*gg.y + bb.y);
    o[2] = f2bf((y[2]-m)*inv*gg.z + bb.z);
    o[3] = f2bf((y[3]-m)*inv*gg.w + bb.w);
    *reinterpret_cast<ushort4v*>(&h1[base + h0]) = o;
}

// ---- out = fp32( LN(G + h1) * g2 + b2 ) ----
__global__ __launch_bounds__(256) void ln2_kernel(
    const unsigned short* __restrict__ Gb, const unsigned short* __restrict__ h1b,
    const float* __restrict__ g2, const float* __restrict__ b2,
    float* __restrict__ out)
{
    const int row = blockIdx.x;
    const size_t base = (size_t)row * HDIM;
    const int h0 = threadIdx.x * 4;

    ushort4v gv = *reinterpret_cast<const ushort4v*>(&Gb[base + h0]);
    ushort4v hv = *reinterpret_cast<const ushort4v*>(&h1b[base + h0]);
    float y[4];
    y[0] = bf2f(gv[0]) + bf2f(hv[0]); y[1] = bf2f(gv[1]) + bf2f(hv[1]);
    y[2] = bf2f(gv[2]) + bf2f(hv[2]); y[3] = bf2f(gv[3]) + bf2f(hv[3]);

    float s = y[0]+y[1]+y[2]+y[3];
    float s2 = y[0]*y[0]+y[1]*y[1]+y[2]*y[2]+y[3]*y[3];
    #pragma unroll
    for (int off = 32; off > 0; off >>= 1) {
        s  += __shfl_down(s,  off);
        s2 += __shfl_down(s2, off);
    }
    __shared__ float ws1[4], ws2[4];
    const int wid = threadIdx.x >> 6;
    if ((threadIdx.x & 63) == 0) { ws1[wid] = s; ws2[wid] = s2; }
    __syncthreads();
    const float S  = ws1[0]+ws1[1]+ws1[2]+ws1[3];
    const float S2 = ws2[0]+ws2[1]+ws2[2]+ws2[3];
    const float m   = S  * (1.0f / HDIM);
    const float var = S2 * (1.0f / HDIM) - m*m;
    const float inv = rsqrtf(var + LNEPS);

    float4 gg = *reinterpret_cast<const float4*>(&g2[h0]);
    float4 bb = *reinterpret_cast<const float4*>(&b2[h0]);
    float4 o;
    o.x = (y[0]-m)*inv*gg.x + bb.x;
    o.y = (y[1]-m)*inv*gg.y + bb.y;
    o.z = (y[2]-m)*inv*gg.z + bb.z;
    o.w = (y[3]-m)*inv*gg.w + bb.w;
    *reinterpret_cast<float4*>(&out[base + h0]) = o;
}

extern "C" void kernel_launch(void* const* d_in, const int* in_sizes, int n_in,
                              void* d_out, int out_size, void* d_ws, size_t ws_size,
                              hipStream_t stream) {
    (void)in_sizes; (void)n_in; (void)out_size; (void)ws_size;
    const float* X  = (const float*)d_in[0];
    const float* Wq = (const float*)d_in[1];
    const float* bq = (const float*)d_in[2];
    const float* Wk = (const float*)d_in[3];
    const float* bk = (const float*)d_in[4];
    const float* Wv = (const float*)d_in[5];
    const float* bv = (const float*)d_in[6];
    const float* Wf = (const float*)d_in[7];
    const float* bf = (const float*)d_in[8];
    const float* g1 = (const float*)d_in[9];
    const float* b1 = (const float*)d_in[10];
    const float* g2 = (const float*)d_in[11];
    const float* b2 = (const float*)d_in[12];
    float* out = (float*)d_out;

    const size_t MATE = (size_t)NB * LLEN * HDIM;   // 16,777,216 elements
    const size_t WE   = (size_t)HDIM * HDIM;        // 1,048,576 elements

    unsigned short* Xb  = (unsigned short*)d_ws;    // 32 MB
    unsigned short* Qb  = Xb + MATE;                // 32 MB
    unsigned short* Kb  = Qb + MATE;                // 32 MB
    unsigned short* WqT = Kb + MATE;                // 2 MB each
    unsigned short* WkT = WqT + WE;
    unsigned short* WvT = WkT + WE;
    unsigned short* WfT = WvT + WE;
    float* colsum = (float*)(WfT + WE);             // 64 KB
    float* diagv  = colsum + (size_t)NB * LLEN;     // 64 KB
    unsigned short* Vb  = (unsigned short*)d_out;   // stage V (bf16) in d_out
    unsigned short* h1b = Qb;                       // reuse after qk
    unsigned short* Gb  = Kb;                       // reuse after qk

    const int M = NB * LLEN;            // 16384
    const float scale = 1.0f / 32.0f;   // 1/sqrt(H)

    hipMemsetAsync(colsum, 0, (size_t)NB * LLEN * sizeof(float), stream);

    const int n8 = (int)(MATE / 8);
    cast_f32_bf16<<<n8 / 256, 256, 0, stream>>>(X, Xb, n8);

    dim3 tgrid(HDIM / 32, HDIM / 32);
    transpose_cast<<<tgrid, 256, 0, stream>>>(Wq, WqT);
    transpose_cast<<<tgrid, 256, 0, stream>>>(Wk, WkT);
    transpose_cast<<<tgrid, 256, 0, stream>>>(Wv, WvT);
    transpose_cast<<<tgrid, 256, 0, stream>>>(Wf, WfT);

    dim3 ggrid(HDIM / TN, M / TM);      // (8, 128)
    gemm_nt_bf16<<<ggrid, 256, 0, stream>>>(Xb, WqT, bq, Qb, M, HDIM, HDIM, scale);
    gemm_nt_bf16<<<ggrid, 256, 0, stream>>>(Xb, WkT, bk, Kb, M, HDIM, HDIM, scale);
    gemm_nt_bf16<<<ggrid, 256, 0, stream>>>(Xb, WvT, bv, Vb, M, HDIM, HDIM, 1.0f);

    dim3 qgrid(LLEN / TN, LLEN / TM, NB);   // (16, 16, 8)
    qk_colsum_diag<<<qgrid, 256, 0, stream>>>(Qb, Kb, colsum, diagv);

    ln1_kernel<<<M, 256, 0, stream>>>(Vb, X, colsum, diagv, g1, b1, h1b);

    gemm_nt_bf16<<<ggrid, 256, 0, stream>>>(h1b, WfT, bf, Gb, M, HDIM, HDIM, 1.0f);

    ln2_kernel<<<M, 256, 0, stream>>>(Gb, h1b, g2, b2, out);
}

// Round 3
// 302.400 us; speedup vs baseline: 9.4390x; 1.3275x over previous
//
#include <hip/hip_runtime.h>
#include <math.h>

#define NB   8
#define LLEN 2048
#define HDIM 1024
#define LNEPS 1e-5f

#define BM 256
#define BN 256
#define BK 64
#define NTHR 512

typedef __attribute__((ext_vector_type(8))) short short8;
typedef __attribute__((ext_vector_type(4))) unsigned short ushort4v;
typedef __attribute__((ext_vector_type(4))) float f32x4;

typedef __attribute__((address_space(3))) void lds_void;
typedef const __attribute__((address_space(1))) void glob_void;

__device__ __forceinline__ unsigned short f2bf(float f) {
    union { float f; unsigned u; } v; v.f = f;
    unsigned r = v.u + 0x7FFFu + ((v.u >> 16) & 1u);
    return (unsigned short)(r >> 16);
}
__device__ __forceinline__ float bf2f(unsigned short h) {
    union { unsigned u; float f; } v; v.u = ((unsigned)h) << 16;
    return v.f;
}

__device__ __forceinline__ void wg_barrier() {
    asm volatile("" ::: "memory");
    __builtin_amdgcn_s_barrier();
    asm volatile("" ::: "memory");
}

// Stage one 256x64 bf16 tile into LDS with XOR-swizzled layout.
// LDS image: byte(r,cb) = r*128 + (cb ^ ((r&7)<<4)).  global_load_lds writes
// linearly (wave-uniform base + lane*16), so the swizzle is applied to the
// per-lane GLOBAL source address (rule 21: both-sides-or-neither).
__device__ __forceinline__ void stage_tile(
    const unsigned short* __restrict__ src, int ldK, int R0, int kcol0,
    unsigned short* ldsDst, int w, int lane)
{
    const int rsub = lane >> 3;                 // row within 8-row group
    const int csw  = 8 * ((lane & 7) ^ rsub);   // swizzled element col
    #pragma unroll
    for (int s = 0; s < 4; ++s) {
        const int r = (s*8 + w)*8 + rsub;       // 0..255
        const unsigned short* g = src + (size_t)(R0 + r) * ldK + kcol0 + csw;
        __builtin_amdgcn_global_load_lds(
            (glob_void*)g, (lds_void*)(ldsDst + (s*8 + w)*512), 16, 0, 0);
    }
}

// ---- C = bf16( alpha * (A @ Bt^T + bias) ); 256x256 tile, depth-2 pipeline ----
__global__ __launch_bounds__(NTHR, 2) void gemm_nt_bf16_256(
    const unsigned short* __restrict__ A,
    const unsigned short* __restrict__ Bt,
    const float* __restrict__ bias,
    unsigned short* __restrict__ C,
    int M, int Nn, int Kk, float alpha, int gx)
{
    __shared__ __align__(16) unsigned short lds[2][2][BM * BK];
    const int t = threadIdx.x, w = t >> 6, l = t & 63;
    const int wr = w >> 2, wc = w & 3;

    // XCD-aware swizzle (bijective: grid % 8 == 0 for all our launches)
    const int nwg = gridDim.x;
    const int bid = blockIdx.x;
    const int swz = (bid & 7) * (nwg >> 3) + (bid >> 3);
    const int bx = swz % gx, by = swz / gx;
    const int rowBase = by * BM, colBase = bx * BN;
    const int NT = Kk / BK;

    f32x4 acc[8][4] = {};

    stage_tile(A,  Kk, rowBase, 0,  &lds[0][0][0], w, l);
    stage_tile(Bt, Kk, colBase, 0,  &lds[0][1][0], w, l);
    stage_tile(A,  Kk, rowBase, BK, &lds[1][0][0], w, l);
    stage_tile(Bt, Kk, colBase, BK, &lds[1][1][0], w, l);
    asm volatile("s_waitcnt vmcnt(8)" ::: "memory");
    wg_barrier();

    const int lr = l & 15;
    const int sw = (l & 7) << 4;
    const int aRowByte = (wr*128 + lr) * 128;
    const int bRowByte = (wc*64  + lr) * 128;
    const int c0 = ((l >> 4) * 16) ^ sw;
    const int c1 = (((l >> 4) * 16) + 64) ^ sw;

    for (int kt = 0; kt < NT; ++kt) {
        const char* bufA = (const char*)&lds[kt & 1][0][0];
        const char* bufB = (const char*)&lds[kt & 1][1][0];
        #pragma unroll
        for (int kk = 0; kk < 2; ++kk) {
            const int cc = kk ? c1 : c0;
            short8 af[8], bfr[4];
            #pragma unroll
            for (int mi = 0; mi < 8; ++mi)
                af[mi] = *(const short8*)(bufA + aRowByte + mi*2048 + cc);
            #pragma unroll
            for (int ni = 0; ni < 4; ++ni)
                bfr[ni] = *(const short8*)(bufB + bRowByte + ni*2048 + cc);
            #pragma unroll
            for (int mi = 0; mi < 8; ++mi)
                #pragma unroll
                for (int ni = 0; ni < 4; ++ni)
                    acc[mi][ni] = __builtin_amdgcn_mfma_f32_16x16x32_bf16(
                        af[mi], bfr[ni], acc[mi][ni], 0, 0, 0);
        }
        if (kt == NT - 1) break;
        wg_barrier();                       // all waves done reading buf[kt&1]
        if (kt + 2 < NT) {
            stage_tile(A,  Kk, rowBase, (kt+2)*BK, &lds[kt&1][0][0], w, l);
            stage_tile(Bt, Kk, colBase, (kt+2)*BK, &lds[kt&1][1][0], w, l);
            asm volatile("s_waitcnt vmcnt(8)" ::: "memory");  // kt+1 landed
        } else {
            asm volatile("s_waitcnt vmcnt(0)" ::: "memory");
        }
        wg_barrier();
    }

    #pragma unroll
    for (int ni = 0; ni < 4; ++ni) {
        const int col = colBase + wc*64 + ni*16 + lr;
        const float bv = bias[col];
        #pragma unroll
        for (int mi = 0; mi < 8; ++mi) {
            const int row0 = rowBase + wr*128 + mi*16 + (l >> 4) * 4;
            #pragma unroll
            for (int j = 0; j < 4; ++j)
                C[(size_t)(row0 + j) * Nn + col] = f2bf(alpha * (acc[mi][ni][j] + bv));
        }
    }
}

// ---- per batch: A[a,b]=Q[a,:]·K[b,:]; colsum[b]+=sum_a exp(A[a,b]); diag[l]=A[l,l] ----
__global__ __launch_bounds__(NTHR, 2) void qk_colsum_diag_256(
    const unsigned short* __restrict__ Q,
    const unsigned short* __restrict__ K,
    float* __restrict__ colsum, float* __restrict__ diagv)
{
    __shared__ __align__(16) unsigned short lds[2][2][BM * BK];
    const int t = threadIdx.x, w = t >> 6, l = t & 63;
    const int wr = w >> 2, wc = w & 3;
    const int n = blockIdx.z;
    const unsigned short* Qn = Q + (size_t)n * LLEN * HDIM;
    const unsigned short* Kn = K + (size_t)n * LLEN * HDIM;
    const int rowBase = blockIdx.y * BM;
    const int colBase = blockIdx.x * BN;
    const int NT = HDIM / BK;

    f32x4 acc[8][4] = {};

    stage_tile(Qn, HDIM, rowBase, 0,  &lds[0][0][0], w, l);
    stage_tile(Kn, HDIM, colBase, 0,  &lds[0][1][0], w, l);
    stage_tile(Qn, HDIM, rowBase, BK, &lds[1][0][0], w, l);
    stage_tile(Kn, HDIM, colBase, BK, &lds[1][1][0], w, l);
    asm volatile("s_waitcnt vmcnt(8)" ::: "memory");
    wg_barrier();

    const int lr = l & 15;
    const int sw = (l & 7) << 4;
    const int aRowByte = (wr*128 + lr) * 128;
    const int bRowByte = (wc*64  + lr) * 128;
    const int c0 = ((l >> 4) * 16) ^ sw;
    const int c1 = (((l >> 4) * 16) + 64) ^ sw;

    for (int kt = 0; kt < NT; ++kt) {
        const char* bufA = (const char*)&lds[kt & 1][0][0];
        const char* bufB = (const char*)&lds[kt & 1][1][0];
        #pragma unroll
        for (int kk = 0; kk < 2; ++kk) {
            const int cc = kk ? c1 : c0;
            short8 af[8], bfr[4];
            #pragma unroll
            for (int mi = 0; mi < 8; ++mi)
                af[mi] = *(const short8*)(bufA + aRowByte + mi*2048 + cc);
            #pragma unroll
            for (int ni = 0; ni < 4; ++ni)
                bfr[ni] = *(const short8*)(bufB + bRowByte + ni*2048 + cc);
            #pragma unroll
            for (int mi = 0; mi < 8; ++mi)
                #pragma unroll
                for (int ni = 0; ni < 4; ++ni)
                    acc[mi][ni] = __builtin_amdgcn_mfma_f32_16x16x32_bf16(
                        af[mi], bfr[ni], acc[mi][ni], 0, 0, 0);
        }
        if (kt == NT - 1) break;
        wg_barrier();
        if (kt + 2 < NT) {
            stage_tile(Qn, HDIM, rowBase, (kt+2)*BK, &lds[kt&1][0][0], w, l);
            stage_tile(Kn, HDIM, colBase, (kt+2)*BK, &lds[kt&1][1][0], w, l);
            asm volatile("s_waitcnt vmcnt(8)" ::: "memory");
        } else {
            asm volatile("s_waitcnt vmcnt(0)" ::: "memory");
        }
        wg_barrier();
    }

    // column sums of exp over this wave's 128 rows
    #pragma unroll
    for (int ni = 0; ni < 4; ++ni) {
        float s = 0.f;
        #pragma unroll
        for (int mi = 0; mi < 8; ++mi)
            #pragma unroll
            for (int j = 0; j < 4; ++j)
                s += __expf(acc[mi][ni][j]);
        s += __shfl_xor(s, 16);
        s += __shfl_xor(s, 32);
        if (l < 16)
            atomicAdd(&colsum[(size_t)n * LLEN + colBase + wc*64 + ni*16 + l], s);
    }

    // diagonal entries (pre-exp)
    if (rowBase == colBase && (wc >> 1) == wr) {
        #pragma unroll
        for (int mi = 0; mi < 8; ++mi)
            #pragma unroll
            for (int ni = 0; ni < 4; ++ni)
                #pragma unroll
                for (int j = 0; j < 4; ++j) {
                    const int rr = wr*128 + mi*16 + (l >> 4)*4 + j;
                    const int cc = wc*64 + ni*16 + lr;
                    if (rr == cc)
                        diagv[(size_t)n * LLEN + rowBase + rr] = acc[mi][ni][j];
                }
    }
}

// ---- fp32 -> bf16 cast, 8 elems/thread ----
__global__ __launch_bounds__(256) void cast_f32_bf16(
    const float* __restrict__ in, unsigned short* __restrict__ outp, int n8)
{
    int i = blockIdx.x * 256 + threadIdx.x;
    if (i >= n8) return;
    const float4* p = reinterpret_cast<const float4*>(in) + (size_t)i * 2;
    float4 a = p[0], b = p[1];
    short8 o;
    o[0] = (short)f2bf(a.x); o[1] = (short)f2bf(a.y);
    o[2] = (short)f2bf(a.z); o[3] = (short)f2bf(a.w);
    o[4] = (short)f2bf(b.x); o[5] = (short)f2bf(b.y);
    o[6] = (short)f2bf(b.z); o[7] = (short)f2bf(b.w);
    *(reinterpret_cast<short8*>(outp) + i) = o;
}

// ---- W (K x N fp32) -> Wt (N x K bf16) ----
__global__ __launch_bounds__(256) void transpose_cast(
    const float* __restrict__ W, unsigned short* __restrict__ Wt)
{
    __shared__ float tile[32][33];
    const int tx = threadIdx.x & 31, ty = threadIdx.x >> 5;
    const int c0 = blockIdx.x * 32, r0 = blockIdx.y * 32;
    #pragma unroll
    for (int r = 0; r < 4; ++r)
        tile[ty + r*8][tx] = W[(size_t)(r0 + ty + r*8) * HDIM + c0 + tx];
    __syncthreads();
    #pragma unroll
    for (int r = 0; r < 4; ++r)
        Wt[(size_t)(c0 + ty + r*8) * HDIM + r0 + tx] = f2bf(tile[tx][ty + r*8]);
}

// ---- h1 = bf16( LN(diag*V + X) * g1 + b1 ) ----
__global__ __launch_bounds__(256) void ln1_kernel(
    const unsigned short* __restrict__ Vb, const float* __restrict__ X,
    const float* __restrict__ colsum, const float* __restrict__ diagval,
    const float* __restrict__ g1, const float* __restrict__ b1,
    unsigned short* __restrict__ h1)
{
    const int row = blockIdx.x;
    const size_t base = (size_t)row * HDIM;
    const float dv = __expf(diagval[row]) / colsum[row];
    const int h0 = threadIdx.x * 4;

    ushort4v vv = *reinterpret_cast<const ushort4v*>(&Vb[base + h0]);
    float4 xx = *reinterpret_cast<const float4*>(&X[base + h0]);
    float y[4];
    y[0] = dv * bf2f(vv[0]) + xx.x; y[1] = dv * bf2f(vv[1]) + xx.y;
    y[2] = dv * bf2f(vv[2]) + xx.z; y[3] = dv * bf2f(vv[3]) + xx.w;

    float s = y[0]+y[1]+y[2]+y[3];
    float s2 = y[0]*y[0]+y[1]*y[1]+y[2]*y[2]+y[3]*y[3];
    #pragma unroll
    for (int off = 32; off > 0; off >>= 1) {
        s  += __shfl_down(s,  off);
        s2 += __shfl_down(s2, off);
    }
    __shared__ float ws1[4], ws2[4];
    const int wid = threadIdx.x >> 6;
    if ((threadIdx.x & 63) == 0) { ws1[wid] = s; ws2[wid] = s2; }
    __syncthreads();
    const float S  = ws1[0]+ws1[1]+ws1[2]+ws1[3];
    const float S2 = ws2[0]+ws2[1]+ws2[2]+ws2[3];
    const float m   = S  * (1.0f / HDIM);
    const float var = S2 * (1.0f / HDIM) - m*m;
    const float inv = rsqrtf(var + LNEPS);

    float4 gg = *reinterpret_cast<const float4*>(&g1[h0]);
    float4 bb = *reinterpret_cast<const float4*>(&b1[h0]);
    ushort4v o;
    o[0] = f2bf((y[0]-m)*inv*gg.x + bb.x);
    o[1] = f2bf((y[1]-m)*inv*gg.y + bb.y);
    o[2] = f2bf((y[2]-m)*inv*gg.z + bb.z);
    o[3] = f2bf((y[3]-m)*inv*gg.w + bb.w);
    *reinterpret_cast<ushort4v*>(&h1[base + h0]) = o;
}

// ---- out = fp32( LN(G + h1) * g2 + b2 ) ----
__global__ __launch_bounds__(256) void ln2_kernel(
    const unsigned short* __restrict__ Gb, const unsigned short* __restrict__ h1b,
    const float* __restrict__ g2, const float* __restrict__ b2,
    float* __restrict__ out)
{
    const int row = blockIdx.x;
    const size_t base = (size_t)row * HDIM;
    const int h0 = threadIdx.x * 4;

    ushort4v gv = *reinterpret_cast<const ushort4v*>(&Gb[base + h0]);
    ushort4v hv = *reinterpret_cast<const ushort4v*>(&h1b[base + h0]);
    float y[4];
    y[0] = bf2f(gv[0]) + bf2f(hv[0]); y[1] = bf2f(gv[1]) + bf2f(hv[1]);
    y[2] = bf2f(gv[2]) + bf2f(hv[2]); y[3] = bf2f(gv[3]) + bf2f(hv[3]);

    float s = y[0]+y[1]+y[2]+y[3];
    float s2 = y[0]*y[0]+y[1]*y[1]+y[2]*y[2]+y[3]*y[3];
    #pragma unroll
    for (int off = 32; off > 0; off >>= 1) {
        s  += __shfl_down(s,  off);
        s2 += __shfl_down(s2, off);
    }
    __shared__ float ws1[4], ws2[4];
    const int wid = threadIdx.x >> 6;
    if ((threadIdx.x & 63) == 0) { ws1[wid] = s; ws2[wid] = s2; }
    __syncthreads();
    const float S  = ws1[0]+ws1[1]+ws1[2]+ws1[3];
    const float S2 = ws2[0]+ws2[1]+ws2[2]+ws2[3];
    const float m   = S  * (1.0f / HDIM);
    const float var = S2 * (1.0f / HDIM) - m*m;
    const float inv = rsqrtf(var + LNEPS);

    float4 gg = *reinterpret_cast<const float4*>(&g2[h0]);
    float4 bb = *reinterpret_cast<const float4*>(&b2[h0]);
    float4 o;
    o.x = (y[0]-m)*inv*gg.x + bb.x;
    o.y = (y[1]-m)*inv*gg.y + bb.y;
    o.z = (y[2]-m)*inv*gg.z + bb.z;
    o.w = (y[3]-m)*inv*gg.w + bb.w;
    *reinterpret_cast<float4*>(&out[base + h0]) = o;
}

extern "C" void kernel_launch(void* const* d_in, const int* in_sizes, int n_in,
                              void* d_out, int out_size, void* d_ws, size_t ws_size,
                              hipStream_t stream) {
    (void)in_sizes; (void)n_in; (void)out_size; (void)ws_size;
    const float* X  = (const float*)d_in[0];
    const float* Wq = (const float*)d_in[1];
    const float* bq = (const float*)d_in[2];
    const float* Wk = (const float*)d_in[3];
    const float* bk = (const float*)d_in[4];
    const float* Wv = (const float*)d_in[5];
    const float* bv = (const float*)d_in[6];
    const float* Wf = (const float*)d_in[7];
    const float* bf = (const float*)d_in[8];
    const float* g1 = (const float*)d_in[9];
    const float* b1 = (const float*)d_in[10];
    const float* g2 = (const float*)d_in[11];
    const float* b2 = (const float*)d_in[12];
    float* out = (float*)d_out;

    const size_t MATE = (size_t)NB * LLEN * HDIM;   // 16,777,216 elements
    const size_t WE   = (size_t)HDIM * HDIM;

    // d_out (64 MiB) doubles as staging: Xb bf16 [0,32MiB), Vb bf16 [32,64MiB).
    // Both are dead before ln2 overwrites d_out with the fp32 result.
    unsigned short* Xb  = (unsigned short*)d_out;
    unsigned short* Vb  = Xb + MATE;

    unsigned short* Qb  = (unsigned short*)d_ws;    // 32 MiB
    unsigned short* Kb  = Qb + MATE;                // 32 MiB
    unsigned short* WqT = Kb + MATE;                // 2 MiB each
    unsigned short* WkT = WqT + WE;
    unsigned short* WvT = WkT + WE;
    unsigned short* WfT = WvT + WE;
    float* colsum = (float*)(WfT + WE);             // 64 KiB
    float* diagv  = colsum + (size_t)NB * LLEN;     // 64 KiB
    unsigned short* h1b = Qb;                       // reuse after qk
    unsigned short* Gb  = Kb;                       // reuse after qk

    const int M = NB * LLEN;            // 16384
    const float scale = 1.0f / 32.0f;   // 1/sqrt(H)

    hipMemsetAsync(colsum, 0, (size_t)NB * LLEN * sizeof(float), stream);

    const int n8 = (int)(MATE / 8);
    cast_f32_bf16<<<n8 / 256, 256, 0, stream>>>(X, Xb, n8);

    dim3 tgrid(HDIM / 32, HDIM / 32);
    transpose_cast<<<tgrid, 256, 0, stream>>>(Wq, WqT);
    transpose_cast<<<tgrid, 256, 0, stream>>>(Wk, WkT);
    transpose_cast<<<tgrid, 256, 0, stream>>>(Wv, WvT);
    transpose_cast<<<tgrid, 256, 0, stream>>>(Wf, WfT);

    const int gx = HDIM / BN;           // 4
    const int nwg = gx * (M / BM);      // 256 blocks (div by 8 -> swizzle OK)
    gemm_nt_bf16_256<<<nwg, NTHR, 0, stream>>>(Xb, WqT, bq, Qb, M, HDIM, HDIM, scale, gx);
    gemm_nt_bf16_256<<<nwg, NTHR, 0, stream>>>(Xb, WkT, bk, Kb, M, HDIM, HDIM, scale, gx);
    gemm_nt_bf16_256<<<nwg, NTHR, 0, stream>>>(Xb, WvT, bv, Vb, M, HDIM, HDIM, 1.0f, gx);

    dim3 qgrid(LLEN / BN, LLEN / BM, NB);   // (8, 8, 8)
    qk_colsum_diag_256<<<qgrid, NTHR, 0, stream>>>(Qb, Kb, colsum, diagv);

    ln1_kernel<<<M, 256, 0, stream>>>(Vb, X, colsum, diagv, g1, b1, h1b);

    gemm_nt_bf16_256<<<nwg, NTHR, 0, stream>>>(h1b, WfT, bf, Gb, M, HDIM, HDIM, 1.0f, gx);

    ln2_kernel<<<M, 256, 0, stream>>>(Gb, h1b, g2, b2, out);
}